// Round 8
// baseline (489.166 us; speedup 1.0000x reference)
//
#include <hip/hip_runtime.h>

typedef __attribute__((ext_vector_type(8))) short short8;
typedef __attribute__((ext_vector_type(4))) float f32x4;

// async global->LDS, 16B per lane. LDS dest = wave-uniform base (+ lane*16 by HW).
#define GLL16(gp, lp) __builtin_amdgcn_global_load_lds( \
    (__attribute__((address_space(1))) void*)(gp), \
    (__attribute__((address_space(3))) void*)(lp), 16, 0, 0)

__device__ __forceinline__ unsigned short f2b(float f) {
  unsigned int u = __builtin_bit_cast(unsigned int, f);
  u += 0x7fffu + ((u >> 16) & 1u);   // RNE; inputs are finite
  return (unsigned short)(u >> 16);
}
__device__ __forceinline__ float b2f(unsigned short s) {
  unsigned int u = ((unsigned int)s) << 16;
  return __builtin_bit_cast(float, u);
}

// ---------------- f32 -> bf16 straight convert (Xd, Xo) ----------------
__global__ __launch_bounds__(256) void conv_k(const float* __restrict__ in,
                                              short8* __restrict__ out, long n8) {
  for (long i = (long)blockIdx.x * 256 + threadIdx.x; i < n8;
       i += (long)gridDim.x * 256) {
    const float4* p = (const float4*)in + 2 * i;
    float4 a = p[0], b = p[1];
    short8 v;
    v[0] = (short)f2b(a.x); v[1] = (short)f2b(a.y);
    v[2] = (short)f2b(a.z); v[3] = (short)f2b(a.w);
    v[4] = (short)f2b(b.x); v[5] = (short)f2b(b.y);
    v[6] = (short)f2b(b.z); v[7] = (short)f2b(b.w);
    out[i] = v;
  }
}

// ------------- transpose+convert weights: in (K x C f32) -> out (C x K bf16) -------------
// inter=1 (Wv): output row for input col c = 4*(c&1023) + (c>>10)  (p = 4d+h head-interleave)
__global__ __launch_bounds__(256) void tconv_k(const float* __restrict__ in,
                                               unsigned short* __restrict__ out,
                                               int K, int C, int inter) {
  __shared__ float t[32][33];
  int k0 = blockIdx.x * 32, c0 = blockIdx.y * 32;
  int tx = threadIdx.x & 31, ty = threadIdx.x >> 5;
#pragma unroll
  for (int p = 0; p < 4; ++p)
    t[ty + p * 8][tx] = in[(size_t)(k0 + ty + p * 8) * C + c0 + tx];
  __syncthreads();
#pragma unroll
  for (int p = 0; p < 4; ++p) {
    int c = ty + p * 8;
    int gc = c0 + c;
    int orow = inter ? ((gc & 1023) * 4 + (gc >> 10)) : gc;
    out[(size_t)orow * K + k0 + tx] = f2b(t[tx][c]);
  }
}

// ======== 256x256 BK=64 quadrant-phase GEMM, cross-phase read pipeline ========
// R8 change: nt-MAJOR block mapping (mtile = lb % NM, nt = lb / NM). Each XCD's
// contiguous lb chunk becomes a COLUMN band (few ntiles x many mtiles), so the
// B-stripe (512KB) is L2-resident per XCD while A streams via L3 (72MB total
// working set, fully L3-cached). Schedule/swizzle identical to R7.
template <int KD, int NTI, int EPI>
__global__ __launch_bounds__(512, 2) void gemm_p(
    const unsigned short* __restrict__ A, const unsigned short* __restrict__ Bt,
    const float* __restrict__ bias, const unsigned short* __restrict__ Qb,
    unsigned short* __restrict__ outb, float* __restrict__ sc,
    float* __restrict__ Z) {
  __shared__ __align__(16) char lds[131072];   // A slots 0..3 x16KB, B at +64KB
  __shared__ float s_sc[1024];

  constexpr int NKT = KD / 64;
  int tid = threadIdx.x;
  int bid = blockIdx.x;
  int cpx = gridDim.x >> 3;                    // grid % 8 == 0 (bijective XCD swizzle)
  int lb = (bid & 7) * cpx + (bid >> 3);
  int nm = gridDim.x / NTI;                    // number of mtiles
  int mtile = lb % nm, nt0 = lb / nm;          // nt-major: XCD chunk = column band
  long m0 = (long)mtile * 256;
  int l = tid & 63, wid = tid >> 6, wm = wid >> 2, wn = wid & 3;

  // staging source mapping (inverse of read swizzle), verified R1-R6:
  // LDS[row][pos16B] holds source chunk pos^(row&7).
  int rowg = tid >> 3;
  int swz = (tid & 7) ^ (rowg & 7);
  const char* aSrc = (const char*)(A + m0 * KD) + (long)rowg * (KD * 2) + swz * 16;
  const char* bSrc = (const char*)(Bt + (long)nt0 * 256 * KD) + (long)rowg * (KD * 2) + swz * 16;
  char* ldsb = (char*)lds;
  int dstOff = wid * 1024;

  auto stageA = [&](int hh, int tt) {
    char* base = ldsb + ((tt & 1) * 32768 + hh * 16384) + dstOff;
    const char* s = aSrc + (long)(hh * 128) * (KD * 2) + tt * 128;
    GLL16(s, base);
    GLL16(s + (long)64 * (KD * 2), base + 8192);
  };
  auto stageB = [&](int hh, int tt) {
    char* base = ldsb + 65536 + ((tt & 1) * 32768 + hh * 16384) + dstOff;
    const char* s = bSrc + (long)(hh * 128) * (KD * 2) + tt * 128;
    GLL16(s, base);
    GLL16(s + (long)64 * (KD * 2), base + 8192);
  };

  // thread-local read offsets (swizzled). row&7 == ar&7 since 16|64-multiples drop out.
  int ar = l & 15, kcl = l >> 4;
  int x0 = ((kcl ^ (ar & 7)) << 4);
  int x1 = (((4 | kcl) ^ (ar & 7)) << 4);
  int thrA = (wm * 64 + ar) * 128;
  int thrB = (wn * 32 + ar) * 128;

  short8 aA[4][2], aB[4][2], b0[2][2], b1[2][2];

#define RD_A(dst, slotoff)                                                  \
  do {                                                                      \
    const char* p_ = ldsb + (slotoff) + thrA;                               \
    _Pragma("unroll") for (int m_ = 0; m_ < 4; ++m_) {                      \
      dst[m_][0] = *(const short8*)(p_ + x0 + m_ * 2048);                   \
      dst[m_][1] = *(const short8*)(p_ + x1 + m_ * 2048);                   \
    }                                                                       \
  } while (0)
#define RD_B(dst, slotoff)                                                  \
  do {                                                                      \
    const char* p_ = ldsb + 65536 + (slotoff) + thrB;                       \
    _Pragma("unroll") for (int n_ = 0; n_ < 2; ++n_) {                      \
      dst[n_][0] = *(const short8*)(p_ + x0 + n_ * 2048);                   \
      dst[n_][1] = *(const short8*)(p_ + x1 + n_ * 2048);                   \
    }                                                                       \
  } while (0)
#define MFQ(q, am, bn)                                                      \
  do {                                                                      \
    __builtin_amdgcn_s_setprio(1);                                          \
    _Pragma("unroll") for (int m_ = 0; m_ < 4; ++m_)                        \
        _Pragma("unroll") for (int n_ = 0; n_ < 2; ++n_)                    \
            _Pragma("unroll") for (int k_ = 0; k_ < 2; ++k_)                \
                acc[q][m_ * 2 + n_] = __builtin_amdgcn_mfma_f32_16x16x32_bf16( \
                    am[m_][k_], bn[n_][k_], acc[q][m_ * 2 + n_], 0, 0, 0);  \
    __builtin_amdgcn_s_setprio(0);                                          \
  } while (0)
#define VM(n) asm volatile("s_waitcnt vmcnt(" #n ")" ::: "memory")
#define BAR() __builtin_amdgcn_s_barrier()
#define CLOB() asm volatile("" ::: "memory")

  f32x4 zero = {0.f, 0.f, 0.f, 0.f};
  f32x4 acc[4][8];
#pragma unroll
  for (int q = 0; q < 4; ++q)
#pragma unroll
    for (int f = 0; f < 8; ++f) acc[q][f] = zero;

  // prologue: tile 0 halves in order [A0,B0,B1,A1]; then (EPI2) s_sc; pre-read aA,b0.
  stageA(0, 0); stageB(0, 0); stageB(1, 0); stageA(1, 0);
  if constexpr (EPI == 2) {
    for (int i = tid; i < 1024; i += 512) s_sc[i] = sc[m0 * 4 + i];
  }
  VM(4); BAR(); CLOB();
  RD_A(aA, 0);
  RD_B(b0, 0);

  for (int t = 0; t < NKT - 1; ++t) {
    int aS = (t & 1) * 32768;
    int bS = aS;                               // B offsets are +65536 inside RD_B
    int aS2 = aS ^ 32768;
    // p0: compute q0(A0,B0); read B1[t]; stage A0[t+1]
    stageA(0, t + 1);
    VM(4); BAR(); CLOB();
    RD_B(b1, bS + 16384);
    MFQ(0, aA, b0);
    // p1: compute q1(A0,B1); read A1[t]; stage B0[t+1]
    stageB(0, t + 1);
    VM(4); BAR(); CLOB();
    RD_A(aB, aS + 16384);
    MFQ(1, aA, b1);
    // p2: compute q2(A1,B0); read A0[t+1]; stage B1[t+1]
    stageB(1, t + 1);
    VM(4); BAR(); CLOB();
    RD_A(aA, aS2);
    MFQ(2, aB, b0);
    // p3: compute q3(A1,B1); read B0[t+1]; stage A1[t+1]
    stageA(1, t + 1);
    VM(4); BAR(); CLOB();
    RD_B(b0, aS2);
    MFQ(3, aB, b1);
  }
  {  // tail tile: no stages, drain progressively
    constexpr int t = NKT - 1;
    int aS = (t & 1) * 32768;
    VM(2); BAR(); CLOB();
    RD_B(b1, aS + 16384);
    MFQ(0, aA, b0);
    VM(0); BAR(); CLOB();
    RD_A(aB, aS + 16384);
    MFQ(1, aA, b1);
    MFQ(2, aB, b0);
    MFQ(3, aB, b1);
  }
#undef RD_A
#undef RD_B
#undef MFQ
#undef VM
#undef BAR
#undef CLOB

  if constexpr (EPI == 0) {
#pragma unroll
    for (int qm = 0; qm < 2; ++qm)
#pragma unroll
      for (int qn = 0; qn < 2; ++qn) {
        int q = qm * 2 + qn;
#pragma unroll
        for (int n = 0; n < 2; ++n) {
          int col = nt0 * 256 + qn * 128 + wn * 32 + n * 16 + (l & 15);
          float bb = bias[col];
#pragma unroll
          for (int m = 0; m < 4; ++m) {
            long rowb = m0 + qm * 128 + wm * 64 + m * 16 + ((l >> 4) << 2);
#pragma unroll
            for (int r = 0; r < 4; ++r)
              outb[(rowb + r) * 512 + col] = f2b(acc[q][m * 2 + n][r] + bb);
          }
        }
      }
  } else if constexpr (EPI == 1) {
    float part[2][2][4][4];
#pragma unroll
    for (int qm = 0; qm < 2; ++qm)
#pragma unroll
      for (int qn = 0; qn < 2; ++qn)
#pragma unroll
        for (int m = 0; m < 4; ++m)
#pragma unroll
          for (int r = 0; r < 4; ++r) part[qm][qn][m][r] = 0.f;
#pragma unroll
    for (int qm = 0; qm < 2; ++qm)
#pragma unroll
      for (int qn = 0; qn < 2; ++qn) {
        int q = qm * 2 + qn;
#pragma unroll
        for (int n = 0; n < 2; ++n) {
          int col = nt0 * 256 + qn * 128 + wn * 32 + n * 16 + (l & 15);
          float bb = bias[col];
#pragma unroll
          for (int m = 0; m < 4; ++m) {
            long rowb = m0 + qm * 128 + wm * 64 + m * 16 + ((l >> 4) << 2);
#pragma unroll
            for (int r = 0; r < 4; ++r) {
              float kv = acc[q][m * 2 + n][r] + bb;
              part[qm][qn][m][r] += kv * b2f(Qb[(rowb + r) * 512 + col]);
            }
          }
        }
      }
    __syncthreads();
    float (*sred)[2][4] = (float(*)[2][4])ldsb;   // [256][head2][wn4] = 8KB
#pragma unroll
    for (int qm = 0; qm < 2; ++qm)
#pragma unroll
      for (int qn = 0; qn < 2; ++qn)
#pragma unroll
        for (int m = 0; m < 4; ++m)
#pragma unroll
          for (int r = 0; r < 4; ++r) {
            float s = part[qm][qn][m][r];
            s += __shfl_xor(s, 1);
            s += __shfl_xor(s, 2);
            s += __shfl_xor(s, 4);
            s += __shfl_xor(s, 8);
            if ((l & 15) == 0)
              sred[qm * 128 + wm * 64 + m * 16 + ((l >> 4) << 2) + r][qn][wn] = s;
          }
    __syncthreads();
    {
      int row = tid >> 1, hh = tid & 1;
      float v = sred[row][hh][0] + sred[row][hh][1] + sred[row][hh][2] +
                sred[row][hh][3];
      sc[(m0 + row) * 4 + nt0 * 2 + hh] = v;
    }
  } else {
    __syncthreads();
    float* Zs = (float*)ldsb;                   // 256 x 64 f32 = 64 KB
#pragma unroll
    for (int qm = 0; qm < 2; ++qm)
#pragma unroll
      for (int qn = 0; qn < 2; ++qn) {
        int q = qm * 2 + qn;
#pragma unroll
        for (int n = 0; n < 2; ++n) {
          int pl = qn * 128 + wn * 32 + n * 16 + (l & 15);   // permuted col p=4d+h
          int pg = nt0 * 256 + pl;
          int h = pl & 3;
          float bb = bias[(pg & 3) * 1024 + (pg >> 2)];
#pragma unroll
          for (int m = 0; m < 4; ++m) {
            int rl = qm * 128 + wm * 64 + m * 16 + ((l >> 4) << 2);
#pragma unroll
            for (int r = 0; r < 4; ++r) {
              float z = s_sc[(rl + r) * 4 + h] * (acc[q][m * 2 + n][r] + bb);
              z = fmaxf(z, __shfl_xor(z, 1));   // max over heads (adjacent p)
              z = fmaxf(z, __shfl_xor(z, 2));
              if ((l & 3) == 0) Zs[(rl + r) * 64 + (pl >> 2)] = z;
            }
          }
        }
      }
    __syncthreads();
#pragma unroll
    for (int it = 0; it < 8; ++it) {            // coalesced float4 stores
      int i = it * 512 + tid;
      int row = i >> 4, d4 = i & 15;
      f32x4 v = *(const f32x4*)&Zs[row * 64 + d4 * 4];
      *(f32x4*)&Z[(m0 + row) * 1024 + nt0 * 64 + d4 * 4] = v;
    }
  }
}

// ---------------- fallback (only if ws too small): fp32, correct but slow ----------------
__global__ __launch_bounds__(256) void naive_k(
    const float* __restrict__ Xd, const float* __restrict__ Xo,
    const float* __restrict__ Wq, const float* __restrict__ bq,
    const float* __restrict__ Wk, const float* __restrict__ bk,
    const float* __restrict__ Wv, const float* __restrict__ bv,
    float* __restrict__ Z) {
  int i = blockIdx.x, t = threadIdx.x;
  __shared__ float xd[1024], xo[512], s[4];
  for (int j = t; j < 1024; j += 256) xd[j] = Xd[(size_t)i * 1024 + j];
  for (int j = t; j < 512; j += 256) xo[j] = Xo[(size_t)i * 512 + j];
  if (t < 4) s[t] = 0.f;
  __syncthreads();
  for (int c = t; c < 512; c += 256) {
    float q = bq[c], k = bk[c];
    for (int j = 0; j < 512; ++j) q += xo[j] * Wq[(size_t)j * 512 + c];
    for (int j = 0; j < 1024; ++j) k += xd[j] * Wk[(size_t)j * 512 + c];
    atomicAdd(&s[c >> 7], q * k);
  }
  __syncthreads();
  for (int d = t; d < 1024; d += 256) {
    float z = -INFINITY;
    for (int h = 0; h < 4; ++h) {
      float v = bv[h * 1024 + d];
      for (int j = 0; j < 1024; ++j) v += xd[j] * Wv[(size_t)j * 4096 + h * 1024 + d];
      z = fmaxf(z, s[h] * v);
    }
    Z[(size_t)i * 1024 + d] = z;
  }
}

extern "C" void kernel_launch(void* const* d_in, const int* in_sizes, int n_in,
                              void* d_out, int out_size, void* d_ws, size_t ws_size,
                              hipStream_t stream) {
  const float* Xd = (const float*)d_in[0];
  const float* Xo = (const float*)d_in[1];
  const float* Wq = (const float*)d_in[2];
  const float* bq = (const float*)d_in[3];
  const float* Wk = (const float*)d_in[4];
  const float* bk = (const float*)d_in[5];
  const float* Wv = (const float*)d_in[6];
  const float* bv = (const float*)d_in[7];
  float* Z = (float*)d_out;
  long N = in_sizes[0] / 1024;

  size_t sz_Xd = (size_t)N * 1024 * 2, sz_Xo = (size_t)N * 512 * 2;
  size_t sz_Wq = (size_t)512 * 512 * 2, sz_Wk = (size_t)512 * 1024 * 2;
  size_t sz_Wv = (size_t)4096 * 1024 * 2;
  size_t sz_Qb = (size_t)N * 512 * 2, sz_sc = (size_t)N * 4 * 4;
  size_t o_Xo = sz_Xd, o_Wq = o_Xo + sz_Xo, o_Wk = o_Wq + sz_Wq,
         o_Wv = o_Wk + sz_Wk, o_Qb = o_Wv + sz_Wv, o_sc = o_Qb + sz_Qb;
  size_t need = o_sc + sz_sc;

  if (ws_size < need || (N % 256) != 0) {
    naive_k<<<(int)N, 256, 0, stream>>>(Xd, Xo, Wq, bq, Wk, bk, Wv, bv, Z);
    return;
  }

  char* w = (char*)d_ws;
  unsigned short* Xd_b = (unsigned short*)w;
  unsigned short* Xo_b = (unsigned short*)(w + o_Xo);
  unsigned short* Wq_t = (unsigned short*)(w + o_Wq);
  unsigned short* Wk_t = (unsigned short*)(w + o_Wk);
  unsigned short* Wv_p = (unsigned short*)(w + o_Wv);
  unsigned short* Qb   = (unsigned short*)(w + o_Qb);
  float* sc = (float*)(w + o_sc);

  conv_k<<<2048, 256, 0, stream>>>(Xd, (short8*)Xd_b, N * 1024 / 8);
  conv_k<<<2048, 256, 0, stream>>>(Xo, (short8*)Xo_b, N * 512 / 8);
  tconv_k<<<dim3(16, 16), 256, 0, stream>>>(Wq, Wq_t, 512, 512, 0);
  tconv_k<<<dim3(32, 16), 256, 0, stream>>>(Wk, Wk_t, 1024, 512, 0);
  tconv_k<<<dim3(32, 128), 256, 0, stream>>>(Wv, Wv_p, 1024, 4096, 1);

  int mt = (int)(N / 256);
  gemm_p<512, 2, 0><<<mt * 2, 512, 0, stream>>>(Xo_b, Wq_t, bq, nullptr, Qb,
                                                nullptr, nullptr);
  gemm_p<1024, 2, 1><<<mt * 2, 512, 0, stream>>>(Xd_b, Wk_t, bk, Qb, nullptr,
                                                 sc, nullptr);
  gemm_p<1024, 16, 2><<<mt * 16, 512, 0, stream>>>(Xd_b, Wv_p, bv, nullptr,
                                                   nullptr, sc, Z);
}

// Round 9
// 472.134 us; speedup vs baseline: 1.0361x; 1.0361x over previous
//
#include <hip/hip_runtime.h>

typedef __attribute__((ext_vector_type(8))) short short8;
typedef __attribute__((ext_vector_type(4))) float f32x4;

// async global->LDS, 16B per lane. LDS dest = wave-uniform base (+ lane*16 by HW).
#define GLL16(gp, lp) __builtin_amdgcn_global_load_lds( \
    (__attribute__((address_space(1))) void*)(gp), \
    (__attribute__((address_space(3))) void*)(lp), 16, 0, 0)

__device__ __forceinline__ unsigned short f2b(float f) {
  unsigned int u = __builtin_bit_cast(unsigned int, f);
  u += 0x7fffu + ((u >> 16) & 1u);   // RNE; inputs are finite
  return (unsigned short)(u >> 16);
}
__device__ __forceinline__ float b2f(unsigned short s) {
  unsigned int u = ((unsigned int)s) << 16;
  return __builtin_bit_cast(float, u);
}

// ---------------- f32 -> bf16 straight convert (Xd, Xo) ----------------
__global__ __launch_bounds__(256) void conv_k(const float* __restrict__ in,
                                              short8* __restrict__ out, long n8) {
  for (long i = (long)blockIdx.x * 256 + threadIdx.x; i < n8;
       i += (long)gridDim.x * 256) {
    const float4* p = (const float4*)in + 2 * i;
    float4 a = p[0], b = p[1];
    short8 v;
    v[0] = (short)f2b(a.x); v[1] = (short)f2b(a.y);
    v[2] = (short)f2b(a.z); v[3] = (short)f2b(a.w);
    v[4] = (short)f2b(b.x); v[5] = (short)f2b(b.y);
    v[6] = (short)f2b(b.z); v[7] = (short)f2b(b.w);
    out[i] = v;
  }
}

// ------------- transpose+convert weights: in (K x C f32) -> out (C x K bf16) -------------
// inter=1 (Wv): output row for input col c = 4*(c&1023) + (c>>10)  (p = 4d+h head-interleave)
__global__ __launch_bounds__(256) void tconv_k(const float* __restrict__ in,
                                               unsigned short* __restrict__ out,
                                               int K, int C, int inter) {
  __shared__ float t[32][33];
  int k0 = blockIdx.x * 32, c0 = blockIdx.y * 32;
  int tx = threadIdx.x & 31, ty = threadIdx.x >> 5;
#pragma unroll
  for (int p = 0; p < 4; ++p)
    t[ty + p * 8][tx] = in[(size_t)(k0 + ty + p * 8) * C + c0 + tx];
  __syncthreads();
#pragma unroll
  for (int p = 0; p < 4; ++p) {
    int c = ty + p * 8;
    int gc = c0 + c;
    int orow = inter ? ((gc & 1023) * 4 + (gc >> 10)) : gc;
    out[(size_t)orow * K + k0 + tx] = f2b(t[tx][c]);
  }
}

// ======== V-GEMM v2: 256x128, BK=32, 8 waves, wave-tile 64x64 (acc=64) ========
// Occupancy-first design: total regs target <=128 (launch_bounds(512,4)) -> 4 waves/SIMD;
// LDS 3-buf ring 24KB each + s_sc = 76KB -> 2 blocks/CU. 16 waves/CU of TLP cover
// staging latency; simple 1-barrier/tile schedule, counted vmcnt(3) (1 spare tile).
// LDS packing (R4-verified): 2 rows per 128B super-row, chunk = (par<<2|kc)^(sr&7).
// Z[row][d] = max_h sc[row][h]*(acc+bv), cols head-interleaved p=4d+h.
template <int KD>
__global__ __launch_bounds__(512, 4) void gemm_v2(
    const unsigned short* __restrict__ A, const unsigned short* __restrict__ Bt,
    const float* __restrict__ bias, const float* __restrict__ sc,
    float* __restrict__ Z) {
  __shared__ __align__(16) char lds[73728];    // 3 bufs x (A 16KB + B 8KB)
  __shared__ float s_sc[1024];

  constexpr int NKT = KD / 32;
  int tid = threadIdx.x;
  int bid = blockIdx.x;
  int cpx = gridDim.x >> 3;                    // grid % 8 == 0 (bijective XCD swizzle)
  int lb = (bid & 7) * cpx + (bid >> 3);
  int mtile = lb >> 5, nt0 = lb & 31;          // 32 ntiles of 128 cols
  long m0 = (long)mtile * 256;
  int l = tid & 63, wid = tid >> 6, wm = wid >> 1, wn = wid & 1;

  // staging source mapping (inverse of read swizzle), R4-verified:
  // dest byte = sr*128 + slot*16 holds global (row = 2*sr+par, kchunk kc),
  // (par<<2|kc) = slot ^ (sr&7).
  int srg = tid >> 3, slot = tid & 7;
  int se = slot ^ (srg & 7);
  int par = se >> 2, kc = se & 3;
  int rowb = srg * 2 + par;                    // row within 128-row group
  const char* aT = (const char*)(A + m0 * KD) + (long)rowb * (KD * 2) + kc * 16;
  const char* bT = (const char*)(Bt + (long)nt0 * 128 * KD) + (long)rowb * (KD * 2) + kc * 16;
  char* ldsb = (char*)lds;
  int dstOff = wid * 1024;                     // wave-uniform dest component

  auto stage = [&](int kt, int bb) {           // one K-tile: A 16KB (2x) + B 8KB (1x)
    int ko = kt * 64;
    GLL16(aT + ko,                  ldsb + bb * 24576 + dstOff);
    GLL16(aT + 128 * (KD * 2) + ko, ldsb + bb * 24576 + 8192 + dstOff);
    GLL16(bT + ko,                  ldsb + bb * 24576 + 16384 + dstOff);
  };

  for (int i = tid; i < 1024; i += 512) s_sc[i] = sc[m0 * 4 + i];

  // read offsets (swizzled), R4-verified formulas
  int ar = l & 15, kcl = l >> 4;
  int aoffR[4], boffR[4];
#pragma unroll
  for (int m = 0; m < 4; ++m) {
    int wr = wm * 64 + m * 16 + ar, sr = wr >> 1;
    aoffR[m] = sr * 128 + (((((wr & 1) << 2) | kcl) ^ (sr & 7)) << 4);
  }
#pragma unroll
  for (int n = 0; n < 4; ++n) {
    int br = wn * 64 + n * 16 + ar, sr = br >> 1;
    boffR[n] = 16384 + sr * 128 + (((((br & 1) << 2) | kcl) ^ (sr & 7)) << 4);
  }

  f32x4 zero = {0.f, 0.f, 0.f, 0.f};
  f32x4 acc[4][4];
#pragma unroll
  for (int m = 0; m < 4; ++m)
#pragma unroll
    for (int n = 0; n < 4; ++n) acc[m][n] = zero;

  stage(0, 0);
  stage(1, 1);                                 // 2-tile prefetch window

  for (int t = 0; t < NKT; ++t) {
    // retire tile t's 3 loads; keep tile t+1's 3 in flight (counted, never drain)
    if (t + 1 < NKT) asm volatile("s_waitcnt vmcnt(3)" ::: "memory");
    else             asm volatile("s_waitcnt vmcnt(0)" ::: "memory");
    __builtin_amdgcn_s_barrier();
    asm volatile("" ::: "memory");
    if (t + 2 < NKT) stage(t + 2, (t + 2) % 3);

    const char* base = ldsb + (t % 3) * 24576;
    short8 af[4], bf[4];
#pragma unroll
    for (int m = 0; m < 4; ++m) af[m] = *(const short8*)(base + aoffR[m]);
#pragma unroll
    for (int n = 0; n < 4; ++n) bf[n] = *(const short8*)(base + boffR[n]);
#pragma unroll
    for (int m = 0; m < 4; ++m)
#pragma unroll
      for (int n = 0; n < 4; ++n)
        acc[m][n] = __builtin_amdgcn_mfma_f32_16x16x32_bf16(af[m], bf[n],
                                                            acc[m][n], 0, 0, 0);
  }

  // ---------------- fused epilogue: scale by scores, max over heads ----------------
  __syncthreads();                             // drain before LDS reuse
  float* Zs = (float*)ldsb;                    // 256 x 32 f32 = 32 KB
#pragma unroll
  for (int n = 0; n < 4; ++n) {
    int pl = wn * 64 + n * 16 + (l & 15);      // local permuted col, p = 4d+h
    int pg = nt0 * 128 + pl;
    int h = pl & 3;
    float bb = bias[(pg & 3) * 1024 + (pg >> 2)];
#pragma unroll
    for (int m = 0; m < 4; ++m) {
      int rl = wm * 64 + m * 16 + ((l >> 4) << 2);
#pragma unroll
      for (int r = 0; r < 4; ++r) {
        float z = s_sc[(rl + r) * 4 + h] * (acc[m][n][r] + bb);
        z = fmaxf(z, __shfl_xor(z, 1));        // max over heads (adjacent p)
        z = fmaxf(z, __shfl_xor(z, 2));
        if ((l & 3) == 0) Zs[(rl + r) * 32 + (pl >> 2)] = z;
      }
    }
  }
  __syncthreads();
#pragma unroll
  for (int it = 0; it < 4; ++it) {             // coalesced float4 stores, 256x32 f32
    int i = it * 512 + tid;
    int row = i >> 3, q = i & 7;
    f32x4 v = *(const f32x4*)&Zs[row * 32 + q * 4];
    *(f32x4*)&Z[(m0 + row) * 1024 + nt0 * 32 + q * 4] = v;
  }
}

// ======== 256x256 BK=64 quadrant-phase GEMM (R7) — Q and K GEMMs ========
template <int KD, int NTI, int EPI>
__global__ __launch_bounds__(512, 2) void gemm_p(
    const unsigned short* __restrict__ A, const unsigned short* __restrict__ Bt,
    const float* __restrict__ bias, const unsigned short* __restrict__ Qb,
    unsigned short* __restrict__ outb, float* __restrict__ sc) {
  __shared__ __align__(16) char lds[131072];   // A slots 0..3 x16KB, B at +64KB

  constexpr int NKT = KD / 64;
  int tid = threadIdx.x;
  int bid = blockIdx.x;
  int cpx = gridDim.x >> 3;
  int lb = (bid & 7) * cpx + (bid >> 3);
  int mtile = lb / NTI, nt0 = lb % NTI;
  long m0 = (long)mtile * 256;
  int l = tid & 63, wid = tid >> 6, wm = wid >> 2, wn = wid & 3;

  int rowg = tid >> 3;
  int swz = (tid & 7) ^ (rowg & 7);
  const char* aSrc = (const char*)(A + m0 * KD) + (long)rowg * (KD * 2) + swz * 16;
  const char* bSrc = (const char*)(Bt + (long)nt0 * 256 * KD) + (long)rowg * (KD * 2) + swz * 16;
  char* ldsb = (char*)lds;
  int dstOff = wid * 1024;

  auto stageA = [&](int hh, int tt) {
    char* base = ldsb + ((tt & 1) * 32768 + hh * 16384) + dstOff;
    const char* s = aSrc + (long)(hh * 128) * (KD * 2) + tt * 128;
    GLL16(s, base);
    GLL16(s + (long)64 * (KD * 2), base + 8192);
  };
  auto stageB = [&](int hh, int tt) {
    char* base = ldsb + 65536 + ((tt & 1) * 32768 + hh * 16384) + dstOff;
    const char* s = bSrc + (long)(hh * 128) * (KD * 2) + tt * 128;
    GLL16(s, base);
    GLL16(s + (long)64 * (KD * 2), base + 8192);
  };

  int ar = l & 15, kcl = l >> 4;
  int x0 = ((kcl ^ (ar & 7)) << 4);
  int x1 = (((4 | kcl) ^ (ar & 7)) << 4);
  int thrA = (wm * 64 + ar) * 128;
  int thrB = (wn * 32 + ar) * 128;

  short8 aA[4][2], aB[4][2], b0[2][2], b1[2][2];

#define RD_A(dst, slotoff)                                                  \
  do {                                                                      \
    const char* p_ = ldsb + (slotoff) + thrA;                               \
    _Pragma("unroll") for (int m_ = 0; m_ < 4; ++m_) {                      \
      dst[m_][0] = *(const short8*)(p_ + x0 + m_ * 2048);                   \
      dst[m_][1] = *(const short8*)(p_ + x1 + m_ * 2048);                   \
    }                                                                       \
  } while (0)
#define RD_B(dst, slotoff)                                                  \
  do {                                                                      \
    const char* p_ = ldsb + 65536 + (slotoff) + thrB;                       \
    _Pragma("unroll") for (int n_ = 0; n_ < 2; ++n_) {                      \
      dst[n_][0] = *(const short8*)(p_ + x0 + n_ * 2048);                   \
      dst[n_][1] = *(const short8*)(p_ + x1 + n_ * 2048);                   \
    }                                                                       \
  } while (0)
#define MFQ(q, am, bn)                                                      \
  do {                                                                      \
    __builtin_amdgcn_s_setprio(1);                                          \
    _Pragma("unroll") for (int m_ = 0; m_ < 4; ++m_)                        \
        _Pragma("unroll") for (int n_ = 0; n_ < 2; ++n_)                    \
            _Pragma("unroll") for (int k_ = 0; k_ < 2; ++k_)                \
                acc[q][m_ * 2 + n_] = __builtin_amdgcn_mfma_f32_16x16x32_bf16( \
                    am[m_][k_], bn[n_][k_], acc[q][m_ * 2 + n_], 0, 0, 0);  \
    __builtin_amdgcn_s_setprio(0);                                          \
  } while (0)
#define VM(n) asm volatile("s_waitcnt vmcnt(" #n ")" ::: "memory")
#define BAR() __builtin_amdgcn_s_barrier()
#define CLOB() asm volatile("" ::: "memory")

  f32x4 zero = {0.f, 0.f, 0.f, 0.f};
  f32x4 acc[4][8];
#pragma unroll
  for (int q = 0; q < 4; ++q)
#pragma unroll
    for (int f = 0; f < 8; ++f) acc[q][f] = zero;

  stageA(0, 0); stageB(0, 0); stageB(1, 0); stageA(1, 0);
  VM(4); BAR(); CLOB();
  RD_A(aA, 0);
  RD_B(b0, 0);

  for (int t = 0; t < NKT - 1; ++t) {
    int aS = (t & 1) * 32768;
    int bS = aS;
    int aS2 = aS ^ 32768;
    stageA(0, t + 1);
    VM(4); BAR(); CLOB();
    RD_B(b1, bS + 16384);
    MFQ(0, aA, b0);
    stageB(0, t + 1);
    VM(4); BAR(); CLOB();
    RD_A(aB, aS + 16384);
    MFQ(1, aA, b1);
    stageB(1, t + 1);
    VM(4); BAR(); CLOB();
    RD_A(aA, aS2);
    MFQ(2, aB, b0);
    stageA(1, t + 1);
    VM(4); BAR(); CLOB();
    RD_B(b0, aS2);
    MFQ(3, aB, b1);
  }
  {
    constexpr int t = NKT - 1;
    int aS = (t & 1) * 32768;
    VM(2); BAR(); CLOB();
    RD_B(b1, aS + 16384);
    MFQ(0, aA, b0);
    VM(0); BAR(); CLOB();
    RD_A(aB, aS + 16384);
    MFQ(1, aA, b1);
    MFQ(2, aB, b0);
    MFQ(3, aB, b1);
  }
#undef RD_A
#undef RD_B
#undef MFQ
#undef VM
#undef BAR
#undef CLOB

  if constexpr (EPI == 0) {
#pragma unroll
    for (int qm = 0; qm < 2; ++qm)
#pragma unroll
      for (int qn = 0; qn < 2; ++qn) {
        int q = qm * 2 + qn;
#pragma unroll
        for (int n = 0; n < 2; ++n) {
          int col = nt0 * 256 + qn * 128 + wn * 32 + n * 16 + (l & 15);
          float bb = bias[col];
#pragma unroll
          for (int m = 0; m < 4; ++m) {
            long rowb = m0 + qm * 128 + wm * 64 + m * 16 + ((l >> 4) << 2);
#pragma unroll
            for (int r = 0; r < 4; ++r)
              outb[(rowb + r) * 512 + col] = f2b(acc[q][m * 2 + n][r] + bb);
          }
        }
      }
  } else {
    float part[2][2][4][4];
#pragma unroll
    for (int qm = 0; qm < 2; ++qm)
#pragma unroll
      for (int qn = 0; qn < 2; ++qn)
#pragma unroll
        for (int m = 0; m < 4; ++m)
#pragma unroll
          for (int r = 0; r < 4; ++r) part[qm][qn][m][r] = 0.f;
#pragma unroll
    for (int qm = 0; qm < 2; ++qm)
#pragma unroll
      for (int qn = 0; qn < 2; ++qn) {
        int q = qm * 2 + qn;
#pragma unroll
        for (int n = 0; n < 2; ++n) {
          int col = nt0 * 256 + qn * 128 + wn * 32 + n * 16 + (l & 15);
          float bb = bias[col];
#pragma unroll
          for (int m = 0; m < 4; ++m) {
            long rowb = m0 + qm * 128 + wm * 64 + m * 16 + ((l >> 4) << 2);
#pragma unroll
            for (int r = 0; r < 4; ++r) {
              float kv = acc[q][m * 2 + n][r] + bb;
              part[qm][qn][m][r] += kv * b2f(Qb[(rowb + r) * 512 + col]);
            }
          }
        }
      }
    __syncthreads();
    float (*sred)[2][4] = (float(*)[2][4])ldsb;   // [256][head2][wn4]
#pragma unroll
    for (int qm = 0; qm < 2; ++qm)
#pragma unroll
      for (int qn = 0; qn < 2; ++qn)
#pragma unroll
        for (int m = 0; m < 4; ++m)
#pragma unroll
          for (int r = 0; r < 4; ++r) {
            float s = part[qm][qn][m][r];
            s += __shfl_xor(s, 1);
            s += __shfl_xor(s, 2);
            s += __shfl_xor(s, 4);
            s += __shfl_xor(s, 8);
            if ((l & 15) == 0)
              sred[qm * 128 + wm * 64 + m * 16 + ((l >> 4) << 2) + r][qn][wn] = s;
          }
    __syncthreads();
    {
      int row = tid >> 1, hh = tid & 1;
      float v = sred[row][hh][0] + sred[row][hh][1] + sred[row][hh][2] +
                sred[row][hh][3];
      sc[(m0 + row) * 4 + nt0 * 2 + hh] = v;
    }
  }
}

// ---------------- fallback (only if ws too small): fp32, correct but slow ----------------
__global__ __launch_bounds__(256) void naive_k(
    const float* __restrict__ Xd, const float* __restrict__ Xo,
    const float* __restrict__ Wq, const float* __restrict__ bq,
    const float* __restrict__ Wk, const float* __restrict__ bk,
    const float* __restrict__ Wv, const float* __restrict__ bv,
    float* __restrict__ Z) {
  int i = blockIdx.x, t = threadIdx.x;
  __shared__ float xd[1024], xo[512], s[4];
  for (int j = t; j < 1024; j += 256) xd[j] = Xd[(size_t)i * 1024 + j];
  for (int j = t; j < 512; j += 256) xo[j] = Xo[(size_t)i * 512 + j];
  if (t < 4) s[t] = 0.f;
  __syncthreads();
  for (int c = t; c < 512; c += 256) {
    float q = bq[c], k = bk[c];
    for (int j = 0; j < 512; ++j) q += xo[j] * Wq[(size_t)j * 512 + c];
    for (int j = 0; j < 1024; ++j) k += xd[j] * Wk[(size_t)j * 512 + c];
    atomicAdd(&s[c >> 7], q * k);
  }
  __syncthreads();
  for (int d = t; d < 1024; d += 256) {
    float z = -INFINITY;
    for (int h = 0; h < 4; ++h) {
      float v = bv[h * 1024 + d];
      for (int j = 0; j < 1024; ++j) v += xd[j] * Wv[(size_t)j * 4096 + h * 1024 + d];
      z = fmaxf(z, s[h] * v);
    }
    Z[(size_t)i * 1024 + d] = z;
  }
}

extern "C" void kernel_launch(void* const* d_in, const int* in_sizes, int n_in,
                              void* d_out, int out_size, void* d_ws, size_t ws_size,
                              hipStream_t stream) {
  const float* Xd = (const float*)d_in[0];
  const float* Xo = (const float*)d_in[1];
  const float* Wq = (const float*)d_in[2];
  const float* bq = (const float*)d_in[3];
  const float* Wk = (const float*)d_in[4];
  const float* bk = (const float*)d_in[5];
  const float* Wv = (const float*)d_in[6];
  const float* bv = (const float*)d_in[7];
  float* Z = (float*)d_out;
  long N = in_sizes[0] / 1024;

  size_t sz_Xd = (size_t)N * 1024 * 2, sz_Xo = (size_t)N * 512 * 2;
  size_t sz_Wq = (size_t)512 * 512 * 2, sz_Wk = (size_t)512 * 1024 * 2;
  size_t sz_Wv = (size_t)4096 * 1024 * 2;
  size_t sz_Qb = (size_t)N * 512 * 2, sz_sc = (size_t)N * 4 * 4;
  size_t o_Xo = sz_Xd, o_Wq = o_Xo + sz_Xo, o_Wk = o_Wq + sz_Wq,
         o_Wv = o_Wk + sz_Wk, o_Qb = o_Wv + sz_Wv, o_sc = o_Qb + sz_Qb;
  size_t need = o_sc + sz_sc;

  if (ws_size < need || (N % 256) != 0) {
    naive_k<<<(int)N, 256, 0, stream>>>(Xd, Xo, Wq, bq, Wk, bk, Wv, bv, Z);
    return;
  }

  char* w = (char*)d_ws;
  unsigned short* Xd_b = (unsigned short*)w;
  unsigned short* Xo_b = (unsigned short*)(w + o_Xo);
  unsigned short* Wq_t = (unsigned short*)(w + o_Wq);
  unsigned short* Wk_t = (unsigned short*)(w + o_Wk);
  unsigned short* Wv_p = (unsigned short*)(w + o_Wv);
  unsigned short* Qb   = (unsigned short*)(w + o_Qb);
  float* sc = (float*)(w + o_sc);

  conv_k<<<2048, 256, 0, stream>>>(Xd, (short8*)Xd_b, N * 1024 / 8);
  conv_k<<<2048, 256, 0, stream>>>(Xo, (short8*)Xo_b, N * 512 / 8);
  tconv_k<<<dim3(16, 16), 256, 0, stream>>>(Wq, Wq_t, 512, 512, 0);
  tconv_k<<<dim3(32, 16), 256, 0, stream>>>(Wk, Wk_t, 1024, 512, 0);
  tconv_k<<<dim3(32, 128), 256, 0, stream>>>(Wv, Wv_p, 1024, 4096, 1);

  int mt = (int)(N / 256);
  gemm_p<512, 2, 0><<<mt * 2, 512, 0, stream>>>(Xo_b, Wq_t, bq, nullptr, Qb,
                                                nullptr);
  gemm_p<1024, 2, 1><<<mt * 2, 512, 0, stream>>>(Xd_b, Wk_t, bk, Qb, nullptr,
                                                 sc);
  gemm_v2<1024><<<mt * 32, 512, 0, stream>>>(Xd_b, Wv_p, bv, sc, Z);
}